// Round 18
// baseline (3891.961 us; speedup 1.0000x reference)
//
#include <hip/hip_runtime.h>
#include <hip/hip_bf16.h>

using bf16x8 = __attribute__((ext_vector_type(8))) __bf16;
using short8 = __attribute__((ext_vector_type(8))) short;
using f32x4  = __attribute__((ext_vector_type(4))) float;
using f4     = __attribute__((ext_vector_type(4))) float;
using i32x4  = __attribute__((ext_vector_type(4))) int;

constexpr int NB = 128;
constexpr int NT = 256;
constexpr int NH = 1024;
constexpr int NE = 256;
constexpr int NV = 256;
constexpr int N3H = 3 * NH;

constexpr int WHH_BYTES = 48 * 2048;
constexpr int TS = 288;                 // tile stride (16 rows x 18 floats)
constexpr int GH_FLOATS = 30 * TS;      // 18 hh + 12 input tiles
constexpr int GH1_FLOATS = 18 * TS;     // de-fused gru1: hh tiles only
constexpr int NBLK = 256;

__device__ __forceinline__ void ldg_sc(i32x4& d, const void* p) {
  asm volatile("global_load_dwordx4 %0, %1, off sc0 sc1" : "=v"(d) : "v"(p));
}
__device__ __forceinline__ void ldg_c(i32x4& d, const void* p) {
  asm volatile("global_load_dwordx4 %0, %1, off" : "=v"(d) : "v"(p));
}
__device__ __forceinline__ void stg_sc(void* p, i32x4 v) {
  asm volatile("global_store_dwordx4 %0, %1, off sc0 sc1" :: "v"(p), "v"(v) : "memory");
}
__device__ __forceinline__ void vm0_fence() {
  asm volatile("s_waitcnt vmcnt(0)" ::: "memory");
}
__device__ __forceinline__ void use_dep(i32x4& d) {
  asm volatile("" : "+v"(d));
}

__device__ __forceinline__ bf16x8 cvt8(const float* p) {
  short8 r;
  #pragma unroll
  for (int j = 0; j < 8; ++j)
    r[j] = (short)__bfloat16_as_ushort(__float2bfloat16(p[j]));
  return __builtin_bit_cast(bf16x8, r);
}
__device__ __forceinline__ float bf2f(unsigned short u) {
  union { unsigned int i; float f; } c; c.i = ((unsigned int)u) << 16; return c.f;
}

__global__ __launch_bounds__(256) void embcvt_kernel(const float* __restrict__ e,
                                                     __hip_bfloat16* __restrict__ o) {
  int i = blockIdx.x * 256 + threadIdx.x;
  o[i] = __float2bfloat16(e[i]);
}

// ============ LAYER 0 (R16, known-good) ============
__global__ __launch_bounds__(384, 1) void gru0_kernel(
    const int* __restrict__ x,
    const __hip_bfloat16* __restrict__ embb,
    const float* __restrict__ Wih,
    const float* __restrict__ Whh,
    const float* __restrict__ bih,
    const float* __restrict__ bhh,
    const float* __restrict__ h0,
    __hip_bfloat16* __restrict__ yout,        // [T][B][H]
    __hip_bfloat16* __restrict__ hbuf,
    float* __restrict__ hout,
    unsigned int* __restrict__ flags)
{
  extern __shared__ char smem[];
  char*  sWhh  = smem;
  float* sGh   = (float*)(smem + WHH_BYTES);
  float* sBias = sGh + GH_FLOATS;
  char*  sH    = (char*)(sBias + 64);

  const int tid  = threadIdx.x;
  const int lane = tid & 63;
  const int wv   = tid >> 6;
  const int mt   = wv & 1;
  const int ks   = wv >> 1;
  const int b    = blockIdx.x;
  const int rb   = (b >> 1) & 3;
  const int cidx = (b & 1) * 32 + (b >> 3);
  const int r0   = rb * 32;
  const int c0   = cidx * 16;
  unsigned int* pf = flags + rb * 64 * 16;
  const int slot = cidx;
  const int l16  = lane & 15;
  const int lk8  = (lane >> 4) * 8;

  for (int it = 0; it < 16; ++it) {
    int idx = it * 384 + tid;
    int gr = idx >> 7, kc = idx & 127;
    int grow = (gr >> 4) * NH + c0 + (gr & 15);
    short8 v = __builtin_bit_cast(short8, cvt8(Whh + grow * NH + kc * 8));
    *(short8*)(sWhh + ((gr * 2048 + kc * 16) ^ ((gr & 7) << 4))) = v;
  }
  if (tid < 16)       sBias[tid] = bih[c0 + tid] + bhh[c0 + tid];
  else if (tid < 32)  { int c = NH + c0 + tid - 16;   sBias[tid] = bih[c] + bhh[c]; }
  else if (tid < 48)  { int c = 2*NH + c0 + tid - 32; sBias[tid] = bih[c]; }
  else if (tid < 64)  { int c = 2*NH + c0 + tid - 48; sBias[tid] = bhh[c]; }

  const int khalf = mt * 128;
  bf16x8 wreg[4];
  #pragma unroll
  for (int kf = 0; kf < 4; ++kf)
    wreg[kf] = cvt8(Wih + (ks * NH + c0 + l16) * NE + khalf + kf * 32 + lk8);

  float hown[2] = {0.f, 0.f};
  #pragma unroll
  for (int ei = 0; ei < 2; ++ei) {
    int e = tid + ei * 384;
    if (e < 512) {
      float hv = h0[(r0 + (e >> 4)) * NH + c0 + (e & 15)];
      hown[ei] = hv;
      ((unsigned short*)sH)[e] = __bfloat16_as_ushort(__float2bfloat16(hv));
    }
  }
  __syncthreads();
  if (tid < 64) {
    i32x4 hv = *(const i32x4*)(sH + (tid >> 1) * 32 + (tid & 1) * 16);
    stg_sc(hbuf + (r0 + (tid >> 1)) * NH + c0 + (tid & 1) * 8, hv);
    vm0_fence();
    if (tid == 0)
      __hip_atomic_store(pf + slot * 16, 1u, __ATOMIC_RELAXED,
                         __HIP_MEMORY_SCOPE_AGENT);
  }

  i32x4 pe0[4], pe1[4];
  int xq0 = x[(r0 + l16) * NT + 0];
  int xq1 = x[(r0 + 16 + l16) * NT + 0];
  {
    const __hip_bfloat16* e0 = embb + xq0 * NE + khalf + lk8;
    const __hip_bfloat16* e1 = embb + xq1 * NE + khalf + lk8;
    #pragma unroll
    for (int kf = 0; kf < 4; ++kf) { ldg_c(pe0[kf], e0 + kf * 32); ldg_c(pe1[kf], e1 + kf * 32); }
    vm0_fence();
    #pragma unroll
    for (int kf = 0; kf < 4; ++kf) { use_dep(pe0[kf]); use_dep(pe1[kf]); }
  }

  for (int t = 0; t < NT; ++t) {
    const __hip_bfloat16* rbuf = hbuf + (t & 1) * (NB * NH);
    __hip_bfloat16* wbuf = hbuf + ((t + 1) & 1) * (NB * NH);
    const int arow = r0 + mt * 16 + l16;
    const int bxor = (l16 & 7) << 4;
    float* abase = sGh + (lane >> 4) * 72 + l16;

    f32x4 ai0 = {0.f,0.f,0.f,0.f}, ai1 = {0.f,0.f,0.f,0.f};
    vm0_fence();
    #pragma unroll
    for (int kf = 0; kf < 4; ++kf) { use_dep(pe0[kf]); use_dep(pe1[kf]); }
    #pragma unroll
    for (int kf = 0; kf < 4; ++kf) {
      ai0 = __builtin_amdgcn_mfma_f32_16x16x32_bf16(
          __builtin_bit_cast(bf16x8, pe0[kf]), wreg[kf], ai0, 0, 0, 0);
      ai1 = __builtin_amdgcn_mfma_f32_16x16x32_bf16(
          __builtin_bit_cast(bf16x8, pe1[kf]), wreg[kf], ai1, 0, 0, 0);
    }
    {
      float* pi0 = abase + (18 + (ks * 2 + mt) * 2 + 0) * TS;
      float* pi1 = abase + (18 + (ks * 2 + mt) * 2 + 1) * TS;
      pi0[0]=ai0[0]; pi0[18]=ai0[1]; pi0[36]=ai0[2]; pi0[54]=ai0[3];
      pi1[0]=ai1[0]; pi1[18]=ai1[1]; pi1[36]=ai1[2]; pi1[54]=ai1[3];
    }

    {
      unsigned int ep = (unsigned int)(t + 1);
      if (tid < 64) {
        const unsigned int* f = pf + tid * 16;
        while (__hip_atomic_load(f, __ATOMIC_RELAXED,
                                 __HIP_MEMORY_SCOPE_AGENT) < ep)
          __builtin_amdgcn_s_sleep(1);
      }
      __syncthreads();
    }

    const int nk = (ks < 2) ? 11 : 10;
    const __hip_bfloat16* aptr = rbuf + arow * NH + lk8;
    i32x4 fr[11];
    #pragma unroll
    for (int i = 0; i < 11; ++i)
      if (i < nk) ldg_sc(fr[i], aptr + (ks + 3 * i) * 32);
    {
      int tn = (t + 1 < NT) ? (t + 1) : (NT - 1);
      xq0 = x[(r0 + l16) * NT + tn];
      xq1 = x[(r0 + 16 + l16) * NT + tn];
    }

    vm0_fence();
    #pragma unroll
    for (int i = 0; i < 11; ++i)
      if (i < nk) use_dep(fr[i]);
    {
      f32x4 ah0 = {0.f,0.f,0.f,0.f}, ah1 = {0.f,0.f,0.f,0.f}, ah2 = {0.f,0.f,0.f,0.f};
      const int bb0 = (l16)      * 2048 + lk8 * 2;
      const int bb1 = (16 + l16) * 2048 + lk8 * 2;
      const int bb2 = (32 + l16) * 2048 + lk8 * 2;
      #pragma unroll
      for (int i = 0; i < 11; ++i) {
        if (i < nk) {
          int kk = ks + 3 * i;
          bf16x8 a = __builtin_bit_cast(bf16x8, fr[i]);
          bf16x8 b0 = __builtin_bit_cast(bf16x8,
              *(const short8*)(sWhh + ((bb0 + kk * 64) ^ bxor)));
          ah0 = __builtin_amdgcn_mfma_f32_16x16x32_bf16(a, b0, ah0, 0, 0, 0);
          bf16x8 b1 = __builtin_bit_cast(bf16x8,
              *(const short8*)(sWhh + ((bb1 + kk * 64) ^ bxor)));
          ah1 = __builtin_amdgcn_mfma_f32_16x16x32_bf16(a, b1, ah1, 0, 0, 0);
          bf16x8 b2 = __builtin_bit_cast(bf16x8,
              *(const short8*)(sWhh + ((bb2 + kk * 64) ^ bxor)));
          ah2 = __builtin_amdgcn_mfma_f32_16x16x32_bf16(a, b2, ah2, 0, 0, 0);
        }
      }
      float* p0 = abase + (ks * 6 + mt * 3 + 0) * TS;
      float* p1 = abase + (ks * 6 + mt * 3 + 1) * TS;
      float* p2 = abase + (ks * 6 + mt * 3 + 2) * TS;
      p0[0]=ah0[0]; p0[18]=ah0[1]; p0[36]=ah0[2]; p0[54]=ah0[3];
      p1[0]=ah1[0]; p1[18]=ah1[1]; p1[36]=ah1[2]; p1[54]=ah1[3];
      p2[0]=ah2[0]; p2[18]=ah2[1]; p2[36]=ah2[2]; p2[54]=ah2[3];
    }
    __syncthreads();

    #pragma unroll
    for (int ei = 0; ei < 2; ++ei) {
      int e = tid + ei * 384;
      if (e < 512) {
        int lrow = e >> 4, lcol = e & 15;
        int m2 = lrow >> 4, off = (lrow & 15) * 18 + lcol;
        float ghr = sGh[(0*6 + m2*3 + 0) * TS + off]
                  + sGh[(1*6 + m2*3 + 0) * TS + off]
                  + sGh[(2*6 + m2*3 + 0) * TS + off];
        float ghz = sGh[(0*6 + m2*3 + 1) * TS + off]
                  + sGh[(1*6 + m2*3 + 1) * TS + off]
                  + sGh[(2*6 + m2*3 + 1) * TS + off];
        float ghn = sGh[(0*6 + m2*3 + 2) * TS + off]
                  + sGh[(1*6 + m2*3 + 2) * TS + off]
                  + sGh[(2*6 + m2*3 + 2) * TS + off];
        float gir = sGh[(18 + (0*2+0)*2 + m2) * TS + off]
                  + sGh[(18 + (0*2+1)*2 + m2) * TS + off];
        float giz = sGh[(18 + (1*2+0)*2 + m2) * TS + off]
                  + sGh[(18 + (1*2+1)*2 + m2) * TS + off];
        float gin = sGh[(18 + (2*2+0)*2 + m2) * TS + off]
                  + sGh[(18 + (2*2+1)*2 + m2) * TS + off];
        float r = 1.f / (1.f + __expf(-(gir + ghr + sBias[lcol])));
        float z = 1.f / (1.f + __expf(-(giz + ghz + sBias[16 + lcol])));
        float npre = (gin + sBias[32 + lcol]) + r * (ghn + sBias[48 + lcol]);
        float n = 2.f / (1.f + __expf(-2.f * npre)) - 1.f;
        float hn = (1.f - z) * n + z * hown[ei];
        hown[ei] = hn;
        ((unsigned short*)sH)[e] = __bfloat16_as_ushort(__float2bfloat16(hn));
      }
    }

    {
      const __hip_bfloat16* e0 = embb + xq0 * NE + khalf + lk8;
      const __hip_bfloat16* e1 = embb + xq1 * NE + khalf + lk8;
      #pragma unroll
      for (int kf = 0; kf < 4; ++kf) { ldg_c(pe0[kf], e0 + kf * 32); ldg_c(pe1[kf], e1 + kf * 32); }
    }

    __syncthreads();
    if (tid >= 64 && tid < 128) {
      int l = tid & 63;
      i32x4 hv = *(const i32x4*)(sH + (l >> 1) * 32 + (l & 1) * 16);
      *(i32x4*)(yout + ((size_t)t * NB + (r0 + (l >> 1))) * NH + c0 + (l & 1) * 8) = hv;
    }
    if (tid < 64) {
      i32x4 hv = *(const i32x4*)(sH + (tid >> 1) * 32 + (tid & 1) * 16);
      stg_sc(wbuf + (r0 + (tid >> 1)) * NH + c0 + (tid & 1) * 8, hv);
      vm0_fence();
      if (tid == 0)
        __hip_atomic_store(pf + slot * 16, (unsigned int)(t + 2),
                           __ATOMIC_RELAXED, __HIP_MEMORY_SCOPE_AGENT);
    }
  }

  #pragma unroll
  for (int ei = 0; ei < 2; ++ei) {
    int e = tid + ei * 384;
    if (e < 512) {
      int lrow = e >> 4, lcol = e & 15;
      hout[(r0 + lrow) * NH + c0 + lcol] = hown[ei];
    }
  }
}

// ============ gi1 = y0 . W_ih1^T (hoisted, only if ws fits) ============
__global__ __launch_bounds__(384, 1) void gi1_kernel(
    const __hip_bfloat16* __restrict__ y0,   // [T][B][H]
    const float* __restrict__ Wih,           // [3H][H]
    __hip_bfloat16* __restrict__ gi)         // [T][B][3H]
{
  const int tid  = threadIdx.x;
  const int lane = tid & 63;
  const int wv   = tid >> 6;
  const int mt   = wv & 1;
  const int ks   = wv >> 1;
  const int cidx = blockIdx.x & 63;
  const int tg   = blockIdx.x >> 6;
  const int c0   = cidx * 16;
  const int l16  = lane & 15;
  const int lk8  = (lane >> 4) * 8;

  bf16x8 wreg[32];
  #pragma unroll
  for (int kf = 0; kf < 32; ++kf)
    wreg[kf] = cvt8(Wih + (ks * NH + c0 + l16) * NH + kf * 32 + lk8);

  for (int tt = 0; tt < 8; ++tt) {
    int t = tg * 8 + tt;
    #pragma unroll
    for (int m4 = 0; m4 < 4; ++m4) {
      int row = mt * 64 + m4 * 16 + l16;
      const __hip_bfloat16* ap = y0 + ((size_t)t * NB + row) * NH + lk8;
      f32x4 acc = {0.f, 0.f, 0.f, 0.f};
      #pragma unroll
      for (int kk = 0; kk < 32; ++kk) {
        bf16x8 a = __builtin_bit_cast(bf16x8, *(const short8*)(ap + kk * 32));
        acc = __builtin_amdgcn_mfma_f32_16x16x32_bf16(a, wreg[kk], acc, 0, 0, 0);
      }
      int orow = mt * 64 + m4 * 16 + (lane >> 4) * 4;
      #pragma unroll
      for (int j = 0; j < 4; ++j)
        gi[((size_t)t * NB + orow + j) * N3H + ks * NH + c0 + l16] =
            __float2bfloat16(acc[j]);
    }
  }
}

// ============ LAYER 1, de-fused: recurrence only (reads gi) ============
__global__ __launch_bounds__(384, 1) void gru1d_kernel(
    const float* __restrict__ Whh,
    const float* __restrict__ bih,
    const float* __restrict__ bhh,
    const float* __restrict__ h0,
    const __hip_bfloat16* __restrict__ gi,    // [T][B][3H]
    __hip_bfloat16* __restrict__ hbuf,
    float* __restrict__ hout,
    unsigned int* __restrict__ flags)
{
  extern __shared__ char smem[];
  char*  sWhh  = smem;
  float* sGh   = (float*)(smem + WHH_BYTES);
  float* sBias = sGh + GH1_FLOATS;
  char*  sH    = (char*)(sBias + 64);

  const int tid  = threadIdx.x;
  const int lane = tid & 63;
  const int wv   = tid >> 6;
  const int mt   = wv & 1;
  const int ks   = wv >> 1;
  const int b    = blockIdx.x;
  const int rb   = (b >> 1) & 3;
  const int cidx = (b & 1) * 32 + (b >> 3);
  const int r0   = rb * 32;
  const int c0   = cidx * 16;
  unsigned int* pf = flags + rb * 64 * 16;
  const int slot = cidx;
  const int l16  = lane & 15;
  const int lk8  = (lane >> 4) * 8;

  for (int it = 0; it < 16; ++it) {
    int idx = it * 384 + tid;
    int gr = idx >> 7, kc = idx & 127;
    int grow = (gr >> 4) * NH + c0 + (gr & 15);
    short8 v = __builtin_bit_cast(short8, cvt8(Whh + grow * NH + kc * 8));
    *(short8*)(sWhh + ((gr * 2048 + kc * 16) ^ ((gr & 7) << 4))) = v;
  }
  if (tid < 16)       sBias[tid] = bih[c0 + tid] + bhh[c0 + tid];
  else if (tid < 32)  { int c = NH + c0 + tid - 16;   sBias[tid] = bih[c] + bhh[c]; }
  else if (tid < 48)  { int c = 2*NH + c0 + tid - 32; sBias[tid] = bih[c]; }
  else if (tid < 64)  { int c = 2*NH + c0 + tid - 48; sBias[tid] = bhh[c]; }

  float hown[2] = {0.f, 0.f};
  #pragma unroll
  for (int ei = 0; ei < 2; ++ei) {
    int e = tid + ei * 384;
    if (e < 512) {
      float hv = h0[(r0 + (e >> 4)) * NH + c0 + (e & 15)];
      hown[ei] = hv;
      ((unsigned short*)sH)[e] = __bfloat16_as_ushort(__float2bfloat16(hv));
    }
  }
  __syncthreads();
  if (tid < 64) {
    i32x4 hv = *(const i32x4*)(sH + (tid >> 1) * 32 + (tid & 1) * 16);
    stg_sc(hbuf + (r0 + (tid >> 1)) * NH + c0 + (tid & 1) * 8, hv);
    vm0_fence();
    if (tid == 0)
      __hip_atomic_store(pf + slot * 16, 1u, __ATOMIC_RELAXED,
                         __HIP_MEMORY_SCOPE_AGENT);
  }

  size_t gioff[2] = {0, 0};
  #pragma unroll
  for (int ei = 0; ei < 2; ++ei) {
    int e = tid + ei * 384;
    if (e < 512)
      gioff[ei] = (size_t)(r0 + (e >> 4)) * N3H + c0 + (e & 15);
  }

  for (int t = 0; t < NT; ++t) {
    const __hip_bfloat16* rbuf = hbuf + (t & 1) * (NB * NH);
    __hip_bfloat16* wbuf = hbuf + ((t + 1) & 1) * (NB * NH);
    const int arow = r0 + mt * 16 + l16;
    const int bxor = (l16 & 7) << 4;
    float* abase = sGh + (lane >> 4) * 72 + l16;

    {
      unsigned int ep = (unsigned int)(t + 1);
      if (tid < 64) {
        const unsigned int* f = pf + tid * 16;
        while (__hip_atomic_load(f, __ATOMIC_RELAXED,
                                 __HIP_MEMORY_SCOPE_AGENT) < ep)
          __builtin_amdgcn_s_sleep(1);
      }
      __syncthreads();
    }

    const int nk = (ks < 2) ? 11 : 10;
    const __hip_bfloat16* aptr = rbuf + arow * NH + lk8;
    i32x4 fr[11];
    #pragma unroll
    for (int i = 0; i < 11; ++i)
      if (i < nk) ldg_sc(fr[i], aptr + (ks + 3 * i) * 32);

    float giv[2][3];
    {
      const __hip_bfloat16* gt = gi + (size_t)t * NB * N3H;
      #pragma unroll
      for (int ei = 0; ei < 2; ++ei) {
        if (tid + ei * 384 < 512) {
          giv[ei][0] = __bfloat162float(gt[gioff[ei]]);
          giv[ei][1] = __bfloat162float(gt[gioff[ei] + NH]);
          giv[ei][2] = __bfloat162float(gt[gioff[ei] + 2 * NH]);
        }
      }
    }

    vm0_fence();
    #pragma unroll
    for (int i = 0; i < 11; ++i)
      if (i < nk) use_dep(fr[i]);
    {
      f32x4 ah0 = {0.f,0.f,0.f,0.f}, ah1 = {0.f,0.f,0.f,0.f}, ah2 = {0.f,0.f,0.f,0.f};
      const int bb0 = (l16)      * 2048 + lk8 * 2;
      const int bb1 = (16 + l16) * 2048 + lk8 * 2;
      const int bb2 = (32 + l16) * 2048 + lk8 * 2;
      #pragma unroll
      for (int i = 0; i < 11; ++i) {
        if (i < nk) {
          int kk = ks + 3 * i;
          bf16x8 a = __builtin_bit_cast(bf16x8, fr[i]);
          bf16x8 b0 = __builtin_bit_cast(bf16x8,
              *(const short8*)(sWhh + ((bb0 + kk * 64) ^ bxor)));
          ah0 = __builtin_amdgcn_mfma_f32_16x16x32_bf16(a, b0, ah0, 0, 0, 0);
          bf16x8 b1 = __builtin_bit_cast(bf16x8,
              *(const short8*)(sWhh + ((bb1 + kk * 64) ^ bxor)));
          ah1 = __builtin_amdgcn_mfma_f32_16x16x32_bf16(a, b1, ah1, 0, 0, 0);
          bf16x8 b2 = __builtin_bit_cast(bf16x8,
              *(const short8*)(sWhh + ((bb2 + kk * 64) ^ bxor)));
          ah2 = __builtin_amdgcn_mfma_f32_16x16x32_bf16(a, b2, ah2, 0, 0, 0);
        }
      }
      float* p0 = abase + (ks * 6 + mt * 3 + 0) * TS;
      float* p1 = abase + (ks * 6 + mt * 3 + 1) * TS;
      float* p2 = abase + (ks * 6 + mt * 3 + 2) * TS;
      p0[0]=ah0[0]; p0[18]=ah0[1]; p0[36]=ah0[2]; p0[54]=ah0[3];
      p1[0]=ah1[0]; p1[18]=ah1[1]; p1[36]=ah1[2]; p1[54]=ah1[3];
      p2[0]=ah2[0]; p2[18]=ah2[1]; p2[36]=ah2[2]; p2[54]=ah2[3];
    }
    __syncthreads();

    #pragma unroll
    for (int ei = 0; ei < 2; ++ei) {
      int e = tid + ei * 384;
      if (e < 512) {
        int lrow = e >> 4, lcol = e & 15;
        int m2 = lrow >> 4, off = (lrow & 15) * 18 + lcol;
        float ghr = sGh[(0*6 + m2*3 + 0) * TS + off]
                  + sGh[(1*6 + m2*3 + 0) * TS + off]
                  + sGh[(2*6 + m2*3 + 0) * TS + off];
        float ghz = sGh[(0*6 + m2*3 + 1) * TS + off]
                  + sGh[(1*6 + m2*3 + 1) * TS + off]
                  + sGh[(2*6 + m2*3 + 1) * TS + off];
        float ghn = sGh[(0*6 + m2*3 + 2) * TS + off]
                  + sGh[(1*6 + m2*3 + 2) * TS + off]
                  + sGh[(2*6 + m2*3 + 2) * TS + off];
        float r = 1.f / (1.f + __expf(-(giv[ei][0] + ghr + sBias[lcol])));
        float z = 1.f / (1.f + __expf(-(giv[ei][1] + ghz + sBias[16 + lcol])));
        float npre = (giv[ei][2] + sBias[32 + lcol]) + r * (ghn + sBias[48 + lcol]);
        float n = 2.f / (1.f + __expf(-2.f * npre)) - 1.f;
        float hn = (1.f - z) * n + z * hown[ei];
        hown[ei] = hn;
        ((unsigned short*)sH)[e] = __bfloat16_as_ushort(__float2bfloat16(hn));
      }
    }

    __syncthreads();
    if (tid < 64) {
      i32x4 hv = *(const i32x4*)(sH + (tid >> 1) * 32 + (tid & 1) * 16);
      stg_sc(wbuf + (r0 + (tid >> 1)) * NH + c0 + (tid & 1) * 8, hv);
      vm0_fence();
      if (tid == 0)
        __hip_atomic_store(pf + slot * 16, (unsigned int)(t + 2),
                           __ATOMIC_RELAXED, __HIP_MEMORY_SCOPE_AGENT);
    }
  }

  #pragma unroll
  for (int ei = 0; ei < 2; ++ei) {
    int e = tid + ei * 384;
    if (e < 512) {
      int lrow = e >> 4, lcol = e & 15;
      hout[(r0 + lrow) * NH + c0 + lcol] = hown[ei];
    }
  }
}

// ============ LAYER 1, fused fallback (R16 behavior, reads y0) ============
__global__ __launch_bounds__(384, 1) void gru1f_kernel(
    const float* __restrict__ Wih,
    const float* __restrict__ Whh,
    const float* __restrict__ bih,
    const float* __restrict__ bhh,
    const float* __restrict__ h0,
    const __hip_bfloat16* __restrict__ yin,   // [T][B][H]
    __hip_bfloat16* __restrict__ hbuf,
    float* __restrict__ hout,
    unsigned int* __restrict__ flags)
{
  extern __shared__ char smem[];
  char*  sWhh  = smem;
  float* sGh   = (float*)(smem + WHH_BYTES);
  float* sBias = sGh + GH_FLOATS;
  char*  sH    = (char*)(sBias + 64);

  const int tid  = threadIdx.x;
  const int lane = tid & 63;
  const int wv   = tid >> 6;
  const int mt   = wv & 1;
  const int ks   = wv >> 1;
  const int b    = blockIdx.x;
  const int rb   = (b >> 1) & 3;
  const int cidx = (b & 1) * 32 + (b >> 3);
  const int r0   = rb * 32;
  const int c0   = cidx * 16;
  unsigned int* pf = flags + rb * 64 * 16;
  const int slot = cidx;
  const int l16  = lane & 15;
  const int lk8  = (lane >> 4) * 8;

  for (int it = 0; it < 16; ++it) {
    int idx = it * 384 + tid;
    int gr = idx >> 7, kc = idx & 127;
    int grow = (gr >> 4) * NH + c0 + (gr & 15);
    short8 v = __builtin_bit_cast(short8, cvt8(Whh + grow * NH + kc * 8));
    *(short8*)(sWhh + ((gr * 2048 + kc * 16) ^ ((gr & 7) << 4))) = v;
  }
  if (tid < 16)       sBias[tid] = bih[c0 + tid] + bhh[c0 + tid];
  else if (tid < 32)  { int c = NH + c0 + tid - 16;   sBias[tid] = bih[c] + bhh[c]; }
  else if (tid < 48)  { int c = 2*NH + c0 + tid - 32; sBias[tid] = bih[c]; }
  else if (tid < 64)  { int c = 2*NH + c0 + tid - 48; sBias[tid] = bhh[c]; }

  const int khalf = mt * 512;
  bf16x8 wreg[16];
  #pragma unroll
  for (int kf = 0; kf < 16; ++kf)
    wreg[kf] = cvt8(Wih + (ks * NH + c0 + l16) * NH + khalf + kf * 32 + lk8);

  float hown[2] = {0.f, 0.f};
  #pragma unroll
  for (int ei = 0; ei < 2; ++ei) {
    int e = tid + ei * 384;
    if (e < 512) {
      float hv = h0[(r0 + (e >> 4)) * NH + c0 + (e & 15)];
      hown[ei] = hv;
      ((unsigned short*)sH)[e] = __bfloat16_as_ushort(__float2bfloat16(hv));
    }
  }
  __syncthreads();
  if (tid < 64) {
    i32x4 hv = *(const i32x4*)(sH + (tid >> 1) * 32 + (tid & 1) * 16);
    stg_sc(hbuf + (r0 + (tid >> 1)) * NH + c0 + (tid & 1) * 8, hv);
    vm0_fence();
    if (tid == 0)
      __hip_atomic_store(pf + slot * 16, 1u, __ATOMIC_RELAXED,
                         __HIP_MEMORY_SCOPE_AGENT);
  }

  i32x4 pe0[16];
  {
    const __hip_bfloat16* yp = yin + ((size_t)0 * NB + (r0 + l16)) * NH + khalf + lk8;
    #pragma unroll
    for (int kf = 0; kf < 16; ++kf) ldg_c(pe0[kf], yp + kf * 32);
    vm0_fence();
    #pragma unroll
    for (int kf = 0; kf < 16; ++kf) use_dep(pe0[kf]);
  }

  for (int t = 0; t < NT; ++t) {
    const __hip_bfloat16* rbuf = hbuf + (t & 1) * (NB * NH);
    __hip_bfloat16* wbuf = hbuf + ((t + 1) & 1) * (NB * NH);
    const int arow = r0 + mt * 16 + l16;
    const int bxor = (l16 & 7) << 4;
    float* abase = sGh + (lane >> 4) * 72 + l16;

    f32x4 ai0 = {0.f,0.f,0.f,0.f}, ai1 = {0.f,0.f,0.f,0.f};
    vm0_fence();
    #pragma unroll
    for (int kf = 0; kf < 16; ++kf) use_dep(pe0[kf]);
    #pragma unroll
    for (int kf = 0; kf < 16; ++kf) {
      ai0 = __builtin_amdgcn_mfma_f32_16x16x32_bf16(
          __builtin_bit_cast(bf16x8, pe0[kf]), wreg[kf], ai0, 0, 0, 0);
    }

    {
      unsigned int ep = (unsigned int)(t + 1);
      if (tid < 64) {
        const unsigned int* f = pf + tid * 16;
        while (__hip_atomic_load(f, __ATOMIC_RELAXED,
                                 __HIP_MEMORY_SCOPE_AGENT) < ep)
          __builtin_amdgcn_s_sleep(1);
      }
      __syncthreads();
    }

    const int nk = (ks < 2) ? 11 : 10;
    const __hip_bfloat16* aptr = rbuf + arow * NH + lk8;
    i32x4 fr[11];
    #pragma unroll
    for (int i = 0; i < 11; ++i)
      if (i < nk) ldg_sc(fr[i], aptr + (ks + 3 * i) * 32);

    {
      const __hip_bfloat16* xp1 = yin + ((size_t)t * NB + (r0 + 16 + l16)) * NH + khalf + lk8;
      #pragma unroll
      for (int kf = 0; kf < 16; ++kf) {
        bf16x8 a = __builtin_bit_cast(bf16x8, *(const short8*)(xp1 + kf * 32));
        ai1 = __builtin_amdgcn_mfma_f32_16x16x32_bf16(a, wreg[kf], ai1, 0, 0, 0);
      }
      float* pi0 = abase + (18 + (ks * 2 + mt) * 2 + 0) * TS;
      float* pi1 = abase + (18 + (ks * 2 + mt) * 2 + 1) * TS;
      pi0[0]=ai0[0]; pi0[18]=ai0[1]; pi0[36]=ai0[2]; pi0[54]=ai0[3];
      pi1[0]=ai1[0]; pi1[18]=ai1[1]; pi1[36]=ai1[2]; pi1[54]=ai1[3];
    }

    vm0_fence();
    #pragma unroll
    for (int i = 0; i < 11; ++i)
      if (i < nk) use_dep(fr[i]);
    {
      f32x4 ah0 = {0.f,0.f,0.f,0.f}, ah1 = {0.f,0.f,0.f,0.f}, ah2 = {0.f,0.f,0.f,0.f};
      const int bb0 = (l16)      * 2048 + lk8 * 2;
      const int bb1 = (16 + l16) * 2048 + lk8 * 2;
      const int bb2 = (32 + l16) * 2048 + lk8 * 2;
      #pragma unroll
      for (int i = 0; i < 11; ++i) {
        if (i < nk) {
          int kk = ks + 3 * i;
          bf16x8 a = __builtin_bit_cast(bf16x8, fr[i]);
          bf16x8 b0 = __builtin_bit_cast(bf16x8,
              *(const short8*)(sWhh + ((bb0 + kk * 64) ^ bxor)));
          ah0 = __builtin_amdgcn_mfma_f32_16x16x32_bf16(a, b0, ah0, 0, 0, 0);
          bf16x8 b1 = __builtin_bit_cast(bf16x8,
              *(const short8*)(sWhh + ((bb1 + kk * 64) ^ bxor)));
          ah1 = __builtin_amdgcn_mfma_f32_16x16x32_bf16(a, b1, ah1, 0, 0, 0);
          bf16x8 b2 = __builtin_bit_cast(bf16x8,
              *(const short8*)(sWhh + ((bb2 + kk * 64) ^ bxor)));
          ah2 = __builtin_amdgcn_mfma_f32_16x16x32_bf16(a, b2, ah2, 0, 0, 0);
        }
      }
      float* p0 = abase + (ks * 6 + mt * 3 + 0) * TS;
      float* p1 = abase + (ks * 6 + mt * 3 + 1) * TS;
      float* p2 = abase + (ks * 6 + mt * 3 + 2) * TS;
      p0[0]=ah0[0]; p0[18]=ah0[1]; p0[36]=ah0[2]; p0[54]=ah0[3];
      p1[0]=ah1[0]; p1[18]=ah1[1]; p1[36]=ah1[2]; p1[54]=ah1[3];
      p2[0]=ah2[0]; p2[18]=ah2[1]; p2[36]=ah2[2]; p2[54]=ah2[3];
    }
    __syncthreads();

    #pragma unroll
    for (int ei = 0; ei < 2; ++ei) {
      int e = tid + ei * 384;
      if (e < 512) {
        int lrow = e >> 4, lcol = e & 15;
        int m2 = lrow >> 4, off = (lrow & 15) * 18 + lcol;
        float ghr = sGh[(0*6 + m2*3 + 0) * TS + off]
                  + sGh[(1*6 + m2*3 + 0) * TS + off]
                  + sGh[(2*6 + m2*3 + 0) * TS + off];
        float ghz = sGh[(0*6 + m2*3 + 1) * TS + off]
                  + sGh[(1*6 + m2*3 + 1) * TS + off]
                  + sGh[(2*6 + m2*3 + 1) * TS + off];
        float ghn = sGh[(0*6 + m2*3 + 2) * TS + off]
                  + sGh[(1*6 + m2*3 + 2) * TS + off]
                  + sGh[(2*6 + m2*3 + 2) * TS + off];
        float gir = sGh[(18 + (0*2+0)*2 + m2) * TS + off]
                  + sGh[(18 + (0*2+1)*2 + m2) * TS + off];
        float giz = sGh[(18 + (1*2+0)*2 + m2) * TS + off]
                  + sGh[(18 + (1*2+1)*2 + m2) * TS + off];
        float gin = sGh[(18 + (2*2+0)*2 + m2) * TS + off]
                  + sGh[(18 + (2*2+1)*2 + m2) * TS + off];
        float r = 1.f / (1.f + __expf(-(gir + ghr + sBias[lcol])));
        float z = 1.f / (1.f + __expf(-(giz + ghz + sBias[16 + lcol])));
        float npre = (gin + sBias[32 + lcol]) + r * (ghn + sBias[48 + lcol]);
        float n = 2.f / (1.f + __expf(-2.f * npre)) - 1.f;
        float hn = (1.f - z) * n + z * hown[ei];
        hown[ei] = hn;
        ((unsigned short*)sH)[e] = __bfloat16_as_ushort(__float2bfloat16(hn));
      }
    }

    {
      int tn = (t + 1 < NT) ? (t + 1) : (NT - 1);
      const __hip_bfloat16* yp = yin + ((size_t)tn * NB + (r0 + l16)) * NH + khalf + lk8;
      #pragma unroll
      for (int kf = 0; kf < 16; ++kf) ldg_c(pe0[kf], yp + kf * 32);
    }

    __syncthreads();
    if (tid < 64) {
      i32x4 hv = *(const i32x4*)(sH + (tid >> 1) * 32 + (tid & 1) * 16);
      stg_sc(wbuf + (r0 + (tid >> 1)) * NH + c0 + (tid & 1) * 8, hv);
      vm0_fence();
      if (tid == 0)
        __hip_atomic_store(pf + slot * 16, (unsigned int)(t + 2),
                           __ATOMIC_RELAXED, __HIP_MEMORY_SCOPE_AGENT);
    }
  }

  #pragma unroll
  for (int ei = 0; ei < 2; ++ei) {
    int e = tid + ei * 384;
    if (e < 512) {
      int lrow = e >> 4, lcol = e & 15;
      hout[(r0 + lrow) * NH + c0 + lcol] = hown[ei];
    }
  }
}

__global__ __launch_bounds__(256) void logits_kernel(
    const __hip_bfloat16* __restrict__ h1,
    const float* __restrict__ fcW,
    const float* __restrict__ fcb,
    float* __restrict__ out)
{
  __shared__ float hrow[NH];
  int b = blockIdx.x, v = threadIdx.x;
  if (v < 128) {
    i32x4 hv;
    ldg_sc(hv, h1 + b * NH + v * 8);
    vm0_fence();
    use_dep(hv);
    short8 s = __builtin_bit_cast(short8, hv);
    #pragma unroll
    for (int j = 0; j < 8; ++j)
      hrow[v * 8 + j] = bf2f((unsigned short)s[j]);
  }
  __syncthreads();
  float acc = fcb[v];
  for (int k = 0; k < NH; k += 4) {
    f4 wv = *(const f4*)(fcW + v * NH + k);
    #pragma unroll
    for (int j = 0; j < 4; ++j) acc += wv[j] * hrow[k + j];
  }
  out[b * NV + v] = acc;
}

extern "C" void kernel_launch(void* const* d_in, const int* in_sizes, int n_in,
                              void* d_out, int out_size, void* d_ws, size_t ws_size,
                              hipStream_t stream) {
  const int*   x    = (const int*)d_in[0];
  const float* h0   = (const float*)d_in[1];
  const float* emb  = (const float*)d_in[2];
  const float* Wih0 = (const float*)d_in[3];
  const float* Whh0 = (const float*)d_in[4];
  const float* bih0 = (const float*)d_in[5];
  const float* bhh0 = (const float*)d_in[6];
  const float* Wih1 = (const float*)d_in[7];
  const float* Whh1 = (const float*)d_in[8];
  const float* bih1 = (const float*)d_in[9];
  const float* bhh1 = (const float*)d_in[10];
  const float* fcW  = (const float*)d_in[11];
  const float* fcb  = (const float*)d_in[12];
  float* out = (float*)d_out;

  const size_t SZ_Y0   = (size_t)NT * NB * NH * 2;     // 64 MB
  const size_t SZ_GI   = (size_t)NT * NB * N3H * 2;    // 201 MB
  const size_t SZ_HBUF = (size_t)2 * NB * NH * 2;
  const size_t SZ_EMB  = (size_t)NV * NE * 2;
  const size_t SZ_FLG  = 4 * 64 * 16 * 4;
  const bool defused = ws_size >= SZ_Y0 + SZ_GI + SZ_HBUF + SZ_EMB + 2 * SZ_FLG;

  char* ws = (char*)d_ws;
  size_t off = 0;
  __hip_bfloat16* y0  = (__hip_bfloat16*)ws;            off += SZ_Y0;
  __hip_bfloat16* gi1 = nullptr;
  if (defused) { gi1 = (__hip_bfloat16*)(ws + off);     off += SZ_GI; }
  __hip_bfloat16* hbuf = (__hip_bfloat16*)(ws + off);   off += SZ_HBUF;
  __hip_bfloat16* embb = (__hip_bfloat16*)(ws + off);   off += SZ_EMB;
  unsigned int*  flags0 = (unsigned int*)(ws + off);    off += SZ_FLG;
  unsigned int*  flags1 = (unsigned int*)(ws + off);    off += SZ_FLG;

  (void)hipMemsetAsync(flags0, 0, 2 * SZ_FLG, stream);
  embcvt_kernel<<<dim3(NV * NE / 256), dim3(256), 0, stream>>>(emb, embb);

  constexpr int lds0 = WHH_BYTES + GH_FLOATS * 4 + 64 * 4 + 1024;   // 134144
  constexpr int lds1 = WHH_BYTES + GH1_FLOATS * 4 + 64 * 4 + 1024;  // 120320
  (void)hipFuncSetAttribute(reinterpret_cast<const void*>(gru0_kernel),
                            hipFuncAttributeMaxDynamicSharedMemorySize, lds0);
  (void)hipFuncSetAttribute(reinterpret_cast<const void*>(gru1d_kernel),
                            hipFuncAttributeMaxDynamicSharedMemorySize, lds1);
  (void)hipFuncSetAttribute(reinterpret_cast<const void*>(gru1f_kernel),
                            hipFuncAttributeMaxDynamicSharedMemorySize, lds0);

  gru0_kernel<<<dim3(NBLK), dim3(384), lds0, stream>>>(
      x, embb, Wih0, Whh0, bih0, bhh0, h0, y0, hbuf, out + 32768, flags0);
  if (defused) {
    gi1_kernel<<<dim3(64 * 32), dim3(384), 0, stream>>>(y0, Wih1, gi1);
    gru1d_kernel<<<dim3(NBLK), dim3(384), lds1, stream>>>(
        Whh1, bih1, bhh1, h0 + NB * NH, gi1, hbuf, out + 32768 + NB * NH, flags1);
  } else {
    gru1f_kernel<<<dim3(NBLK), dim3(384), lds0, stream>>>(
        Wih1, Whh1, bih1, bhh1, h0 + NB * NH, y0, hbuf,
        out + 32768 + NB * NH, flags1);
  }
  logits_kernel<<<dim3(NB), dim3(256), 0, stream>>>(hbuf, fcW, fcb, out);
}